// Round 1
// baseline (113.258 us; speedup 1.0000x reference)
//
#include <hip/hip_runtime.h>
#include <hip/hip_bf16.h>

typedef float f32x4 __attribute__((ext_vector_type(4)));
typedef short s16x8 __attribute__((ext_vector_type(8)));

#define L2E 1.44269504088896340736f

static __device__ __forceinline__ unsigned int bf16_rne(float f) {
    unsigned int u = __builtin_bit_cast(unsigned int, f);
    return (u + 0x7fffu + ((u >> 16) & 1u)) >> 16;
}
static __device__ __forceinline__ unsigned int pack_bf16x2(float lo, float hi) {
    return bf16_rne(lo) | (bf16_rne(hi) << 16);
}

// ---------------------------------------------------------------------------
// Prep: q' = (q+pos)*0.125 -> bf16 [b][t][c]; k' = (k+pos) -> bf16 [b][t][c];
//       v' = (v+pos) -> bf16 [b][c][t]  (natural layout)
// ---------------------------------------------------------------------------
__global__ __launch_bounds__(256) void qkv_prep(const float* __restrict__ qkv,
                                                const float* __restrict__ pos,
                                                unsigned short* __restrict__ qs,
                                                unsigned short* __restrict__ kt,
                                                unsigned short* __restrict__ vt)
{
    __shared__ unsigned short QtS[64][72];
    __shared__ unsigned short KtS[64][72];
    const int b    = blockIdx.y;
    const int t0   = blockIdx.x * 64;
    const int i    = threadIdx.x;
    const int crow = i >> 2;          // 0..63 : channel row
    const int t16  = (i & 3) * 16;    // 0,16,32,48 : t offset

    float pr[16];
    {
        const float* pp = pos + ((size_t)(b * 64 + crow)) * 2048 + t0 + t16;
        #pragma unroll
        for (int j = 0; j < 4; ++j) {
            float4 v = reinterpret_cast<const float4*>(pp)[j];
            pr[4*j+0] = v.x; pr[4*j+1] = v.y; pr[4*j+2] = v.z; pr[4*j+3] = v.w;
        }
    }
    const float* qp = qkv + ((size_t)(b * 192 + crow)) * 2048 + t0 + t16;
    {   // Q -> LDS transposed, scaled by 1/8 (both scale factors folded)
        #pragma unroll
        for (int j = 0; j < 4; ++j) {
            float4 v = reinterpret_cast<const float4*>(qp)[j];
            QtS[t16 + 4*j + 0][crow] = (unsigned short)bf16_rne((v.x + pr[4*j+0]) * 0.125f);
            QtS[t16 + 4*j + 1][crow] = (unsigned short)bf16_rne((v.y + pr[4*j+1]) * 0.125f);
            QtS[t16 + 4*j + 2][crow] = (unsigned short)bf16_rne((v.z + pr[4*j+2]) * 0.125f);
            QtS[t16 + 4*j + 3][crow] = (unsigned short)bf16_rne((v.w + pr[4*j+3]) * 0.125f);
        }
    }
    {   // K -> LDS transposed
        const float* kp = qp + (size_t)64 * 2048;
        #pragma unroll
        for (int j = 0; j < 4; ++j) {
            float4 v = reinterpret_cast<const float4*>(kp)[j];
            KtS[t16 + 4*j + 0][crow] = (unsigned short)bf16_rne(v.x + pr[4*j+0]);
            KtS[t16 + 4*j + 1][crow] = (unsigned short)bf16_rne(v.y + pr[4*j+1]);
            KtS[t16 + 4*j + 2][crow] = (unsigned short)bf16_rne(v.z + pr[4*j+2]);
            KtS[t16 + 4*j + 3][crow] = (unsigned short)bf16_rne(v.w + pr[4*j+3]);
        }
    }
    {   // V: straight through, natural [c][t] layout
        const float* vp = qp + (size_t)128 * 2048;
        unsigned int vv[8];
        #pragma unroll
        for (int j = 0; j < 4; ++j) {
            float4 v = reinterpret_cast<const float4*>(vp)[j];
            vv[2*j+0] = pack_bf16x2(v.x + pr[4*j+0], v.y + pr[4*j+1]);
            vv[2*j+1] = pack_bf16x2(v.z + pr[4*j+2], v.w + pr[4*j+3]);
        }
        unsigned short* dst = vt + ((size_t)(b * 64 + crow)) * 2048 + t0 + t16;
        reinterpret_cast<uint4*>(dst)[0] = make_uint4(vv[0], vv[1], vv[2], vv[3]);
        reinterpret_cast<uint4*>(dst)[1] = make_uint4(vv[4], vv[5], vv[6], vv[7]);
    }
    __syncthreads();
    {   // write out [t][c]
        const int trow = i >> 2;
        const int c16  = (i & 3) * 16;
        uint4 a0 = *reinterpret_cast<const uint4*>(&QtS[trow][c16]);
        uint4 a1 = *reinterpret_cast<const uint4*>(&QtS[trow][c16 + 8]);
        unsigned short* qd = qs + ((size_t)(b * 2048 + t0 + trow)) * 64 + c16;
        reinterpret_cast<uint4*>(qd)[0] = a0;
        reinterpret_cast<uint4*>(qd)[1] = a1;
        uint4 b0 = *reinterpret_cast<const uint4*>(&KtS[trow][c16]);
        uint4 b1 = *reinterpret_cast<const uint4*>(&KtS[trow][c16 + 8]);
        unsigned short* kd = kt + ((size_t)(b * 2048 + t0 + trow)) * 64 + c16;
        reinterpret_cast<uint4*>(kd)[0] = b0;
        reinterpret_cast<uint4*>(kd)[1] = b1;
    }
}

// ---------------------------------------------------------------------------
// Flash attention, swapped orientation (S^T = K·Q^T, O^T = V^T·P^T).
// Block: 4 waves x 16 q-rows = 64 q-rows; loop over 32 s-tiles of 64.
// ---------------------------------------------------------------------------
__global__ __launch_bounds__(256) void attn_kernel(const unsigned short* __restrict__ qs,
                                                   const unsigned short* __restrict__ kt,
                                                   const unsigned short* __restrict__ vt,
                                                   const void* __restrict__ maskp,
                                                   float* __restrict__ out)
{
    __shared__ unsigned short Klds[64][72];  // [s_local][c], pad +8 bf16
    __shared__ unsigned short Vlds[64][72];  // [c][s_local]
    __shared__ unsigned char  Mlds[64][80];  // [t_local][s_local] bytes

    const int b    = blockIdx.y;
    const int t0   = blockIdx.x * 64;
    const int tid  = threadIdx.x;
    const int wave = tid >> 6;
    const int lane = tid & 63;
    const int ln   = lane & 15;
    const int lg   = lane >> 4;

    // --- mask dtype detection (uniform across all threads/blocks) ---
    // int32 0/1 values have bytes 1..3 == 0; packed random bools don't.
    unsigned int accm = 0;
    {
        const unsigned int* mu = (const unsigned int*)maskp;
        #pragma unroll
        for (int j = 0; j < 16; ++j) accm |= mu[j];
    }
    const bool maskIsBool = (accm & 0xffffff00u) != 0u;

    // --- Q fragments (B-operand of swapped QK^T), held for entire kernel ---
    const int tg = t0 + 16 * wave + ln;  // this lane's q row (column of S^T)
    s16x8 qf[2];
    #pragma unroll
    for (int kc = 0; kc < 2; ++kc)
        qf[kc] = *reinterpret_cast<const s16x8*>(
            qs + ((size_t)(b * 2048 + tg)) * 64 + 32 * kc + 8 * lg);

    f32x4 acc[4];
    #pragma unroll
    for (int n = 0; n < 4; ++n) acc[n] = (f32x4){0.f, 0.f, 0.f, 0.f};
    float M = -3.0e38f, L = 0.0f;

    const int stRow = tid >> 2;          // 0..63
    const int stC16 = (tid & 3) * 16;    // 0,16,32,48

    for (int st = 0; st < 32; ++st) {
        const int s0 = st * 64;
        {   // stage K tile [s][c]
            const unsigned short* src = kt + ((size_t)(b * 2048 + s0 + stRow)) * 64 + stC16;
            uint4 a0 = reinterpret_cast<const uint4*>(src)[0];
            uint4 a1 = reinterpret_cast<const uint4*>(src)[1];
            *reinterpret_cast<uint4*>(&Klds[stRow][stC16])     = a0;
            *reinterpret_cast<uint4*>(&Klds[stRow][stC16 + 8]) = a1;
        }
        {   // stage V tile [c][s]
            const unsigned short* src = vt + ((size_t)(b * 64 + stRow)) * 2048 + s0 + stC16;
            uint4 a0 = reinterpret_cast<const uint4*>(src)[0];
            uint4 a1 = reinterpret_cast<const uint4*>(src)[1];
            *reinterpret_cast<uint4*>(&Vlds[stRow][stC16])     = a0;
            *reinterpret_cast<uint4*>(&Vlds[stRow][stC16 + 8]) = a1;
        }
        if (maskIsBool) {  // stage mask tile [t][s] as bytes
            const unsigned char* src = (const unsigned char*)maskp +
                ((size_t)b * 2048 + (size_t)(t0 + stRow)) * 2048 + s0 + stC16;
            *reinterpret_cast<uint4*>(&Mlds[stRow][stC16]) =
                *reinterpret_cast<const uint4*>(src);
        } else {           // int32 mask -> compact to bytes
            const unsigned int* src = (const unsigned int*)maskp +
                ((size_t)b * 2048 + (size_t)(t0 + stRow)) * 2048 + s0 + stC16;
            uint4 x0 = reinterpret_cast<const uint4*>(src)[0];
            uint4 x1 = reinterpret_cast<const uint4*>(src)[1];
            uint4 x2 = reinterpret_cast<const uint4*>(src)[2];
            uint4 x3 = reinterpret_cast<const uint4*>(src)[3];
            auto p4 = [](uint4 x) {
                return (x.x ? 1u : 0u) | ((x.y ? 1u : 0u) << 8) |
                       ((x.z ? 1u : 0u) << 16) | ((x.w ? 1u : 0u) << 24);
            };
            *reinterpret_cast<uint4*>(&Mlds[stRow][stC16]) =
                make_uint4(p4(x0), p4(x1), p4(x2), p4(x3));
        }
        __syncthreads();

        // --- QK^T (swapped): S^T[s][t], lane holds s = s0+16ti+4lg+r, t = tg ---
        f32x4 S[4];
        #pragma unroll
        for (int ti = 0; ti < 4; ++ti) S[ti] = (f32x4){0.f, 0.f, 0.f, 0.f};
        #pragma unroll
        for (int kc = 0; kc < 2; ++kc) {
            #pragma unroll
            for (int ti = 0; ti < 4; ++ti) {
                s16x8 kf = *reinterpret_cast<const s16x8*>(
                    &Klds[16 * ti + ln][32 * kc + 8 * lg]);
                S[ti] = __builtin_amdgcn_mfma_f32_16x16x32_bf16(kf, qf[kc], S[ti], 0, 0, 0);
            }
        }

        // --- mask + online softmax (per-lane over its own q-row column) ---
        float p[4][4];
        const int mrow = 16 * wave + ln;
        #pragma unroll
        for (int ti = 0; ti < 4; ++ti) {
            unsigned int m32 = *reinterpret_cast<const unsigned int*>(
                &Mlds[mrow][16 * ti + 4 * lg]);
            #pragma unroll
            for (int r = 0; r < 4; ++r)
                p[ti][r] = ((m32 >> (8 * r)) & 0xffu) ? -1e9f : S[ti][r];
        }
        float tm = -3.0e38f;
        #pragma unroll
        for (int ti = 0; ti < 4; ++ti)
            #pragma unroll
            for (int r = 0; r < 4; ++r) tm = fmaxf(tm, p[ti][r]);
        tm = fmaxf(tm, __shfl_xor(tm, 16, 64));
        tm = fmaxf(tm, __shfl_xor(tm, 32, 64));
        const float Mn    = fmaxf(M, tm);
        const float alpha = exp2f((M - Mn) * L2E);
        float tsum = 0.f;
        #pragma unroll
        for (int ti = 0; ti < 4; ++ti)
            #pragma unroll
            for (int r = 0; r < 4; ++r) {
                p[ti][r] = exp2f((p[ti][r] - Mn) * L2E);
                tsum += p[ti][r];
            }
        tsum += __shfl_xor(tsum, 16, 64);
        tsum += __shfl_xor(tsum, 32, 64);
        L = L * alpha + tsum;
        M = Mn;
        #pragma unroll
        for (int n = 0; n < 4; ++n) acc[n] *= alpha;

        // --- pack P to bf16 and redistribute to PV B-fragment layout ---
        unsigned int pk[4][2];
        #pragma unroll
        for (int ti = 0; ti < 4; ++ti) {
            pk[ti][0] = pack_bf16x2(p[ti][0], p[ti][1]);
            pk[ti][1] = pack_bf16x2(p[ti][2], p[ti][3]);
        }
        // B-frag dword d for (lane lg, chunk kc2): value pk[2*kc2+(lg>>1)][d&1]
        // from lane ln + 16*(2*(lg&1) + (d>>1)).
        unsigned int pf[2][4];
        #pragma unroll
        for (int kc2 = 0; kc2 < 2; ++kc2)
            #pragma unroll
            for (int a2 = 0; a2 < 2; ++a2)
                #pragma unroll
                for (int b2 = 0; b2 < 2; ++b2)
                    #pragma unroll
                    for (int e = 0; e < 2; ++e) {
                        int src = ln + 16 * (2 * (lg & 1) + e);
                        unsigned int v = (unsigned int)__shfl(
                            (int)pk[2 * kc2 + a2][b2], src, 64);
                        if ((lg >> 1) == a2) pf[kc2][2 * e + b2] = v;
                    }

        // --- PV: O^T[c][t] += V^T · P^T ---
        #pragma unroll
        for (int kc2 = 0; kc2 < 2; ++kc2) {
            union { unsigned int u[4]; s16x8 s; } pu;
            pu.u[0] = pf[kc2][0]; pu.u[1] = pf[kc2][1];
            pu.u[2] = pf[kc2][2]; pu.u[3] = pf[kc2][3];
            #pragma unroll
            for (int n = 0; n < 4; ++n) {
                s16x8 vf = *reinterpret_cast<const s16x8*>(
                    &Vlds[16 * n + ln][32 * kc2 + 8 * lg]);
                acc[n] = __builtin_amdgcn_mfma_f32_16x16x32_bf16(vf, pu.s, acc[n], 0, 0, 0);
            }
        }
        __syncthreads();
    }

    // --- epilogue: normalize and store, coalesced along t ---
    const float inv = 1.0f / L;
    #pragma unroll
    for (int n = 0; n < 4; ++n)
        #pragma unroll
        for (int r = 0; r < 4; ++r)
            out[((size_t)(b * 64 + 16 * n + 4 * lg + r)) * 2048 + t0 + 16 * wave + ln] =
                acc[n][r] * inv;
}

extern "C" void kernel_launch(void* const* d_in, const int* in_sizes, int n_in,
                              void* d_out, int out_size, void* d_ws, size_t ws_size,
                              hipStream_t stream) {
    const float* qkv = (const float*)d_in[0];
    const float* pos = (const float*)d_in[1];
    const void*  msk = d_in[2];
    float* outp = (float*)d_out;
    unsigned short* ws = (unsigned short*)d_ws;
    const size_t PLANE = (size_t)16 * 2048 * 64;   // elements per prepped tensor
    unsigned short* qs = ws;
    unsigned short* kt = ws + PLANE;
    unsigned short* vt = ws + 2 * PLANE;

    dim3 grid(2048 / 64, 16);
    qkv_prep<<<grid, 256, 0, stream>>>(qkv, pos, qs, kt, vt);
    attn_kernel<<<grid, 256, 0, stream>>>(qs, kt, vt, msk, outp);
}